// Round 6
// baseline (99.465 us; speedup 1.0000x reference)
//
#include <hip/hip_runtime.h>
#include <math.h>

// Problem constants
#define BB 4
#define NN 8192
#define KK 16
#define DD 128
#define NPTS (BB * NN)          // 32768
#define FBLOCKS 1024            // 4 blocks/CU on 256 CUs -> all resident
#define BPX 128                 // blocks per xcd-group (FBLOCKS/8)
#define PAD 16                  // 64B line padding for atomic targets
#define BN_EPS 1e-5f

// ---------------------------------------------------------------------------
// Kernel 0: transpose proj_w -> wt[c][d] = w[d][c]; block 0 also zeroes the
// atomic/barrier area (replaces the hipMemsetAsync dispatch). Kernel-boundary
// ordering makes these plain stores visible to fused_gbn's atomics.
// ---------------------------------------------------------------------------
__global__ void transpose_w(const float* __restrict__ w, float* __restrict__ wt,
                            float* gacc, int* cntx, int* cntg, int* genx) {
    if (blockIdx.x == 0) {
        for (int j = threadIdx.x; j < 256 * PAD; j += 256) gacc[j] = 0.f;
        if (threadIdx.x < 8) {
            cntx[threadIdx.x * PAD] = 0;
            genx[threadIdx.x * PAD] = 0;
        }
        if (threadIdx.x == 0) *cntg = 0;
    }
    int i = blockIdx.x * 256 + threadIdx.x;   // 16384 elements
    int d = i >> 7;
    int c = i & 127;
    wt[c * 128 + d] = w[d * 128 + c];
}

// ---------------------------------------------------------------------------
// Kernel 1: h[p][d] = sum_c x[p][c] * wt[c][d]
// 16-row tile -> 2048 blocks (8/CU, 32 waves/CU ceiling). Thread tile 2x4.
// ---------------------------------------------------------------------------
__global__ __launch_bounds__(256) void gemm_h(const float* __restrict__ x,
                                              const float* __restrict__ wt,
                                              float* __restrict__ h) {
    __shared__ float xs[16][128];   // 8 KB
    const int block_row = blockIdx.x * 16;
    const int t = threadIdx.x;

    const float4* xg = reinterpret_cast<const float4*>(x + (size_t)block_row * 128);
    float4* xs4 = reinterpret_cast<float4*>(&xs[0][0]);
#pragma unroll
    for (int i = 0; i < 2; ++i) xs4[t + 256 * i] = xg[t + 256 * i];
    __syncthreads();

    const int ty = t >> 5;          // 0..7
    const int tx = t & 31;          // 0..31
    const int r0 = ty * 2;
    const int c0 = tx * 4;

    float acc[2][4];
#pragma unroll
    for (int r = 0; r < 2; ++r)
#pragma unroll
        for (int j = 0; j < 4; ++j) acc[r][j] = 0.f;

#pragma unroll 4
    for (int c4 = 0; c4 < 32; ++c4) {
        float4 wv[4];
#pragma unroll
        for (int j = 0; j < 4; ++j)
            wv[j] = *reinterpret_cast<const float4*>(wt + (size_t)(c4 * 4 + j) * 128 + c0);
#pragma unroll
        for (int r = 0; r < 2; ++r) {
            float4 xv = *reinterpret_cast<const float4*>(&xs[r0 + r][c4 * 4]);
            const float xc[4] = {xv.x, xv.y, xv.z, xv.w};
#pragma unroll
            for (int j = 0; j < 4; ++j) {
                acc[r][0] = fmaf(xc[j], wv[j].x, acc[r][0]);
                acc[r][1] = fmaf(xc[j], wv[j].y, acc[r][1]);
                acc[r][2] = fmaf(xc[j], wv[j].z, acc[r][2]);
                acc[r][3] = fmaf(xc[j], wv[j].w, acc[r][3]);
            }
        }
    }

#pragma unroll
    for (int r = 0; r < 2; ++r) {
        float4 o = make_float4(acc[r][0], acc[r][1], acc[r][2], acc[r][3]);
        *reinterpret_cast<float4*>(h + (size_t)(block_row + r0 + r) * 128 + c0) = o;
    }
}

// ---------------------------------------------------------------------------
// Kernel 2 (fused): gather (explicit 8-deep prefetch) -> padded atomic BN
// accumulate -> hierarchical grid barrier (read-polling) -> redundant stats
// -> apply+store.
// ---------------------------------------------------------------------------
__global__ __launch_bounds__(256, 4) void fused_gbn(const float* __restrict__ h,
                                                    const float* __restrict__ xyz,
                                                    const int* __restrict__ knn,
                                                    const float* __restrict__ coor,
                                                    const float* __restrict__ scale,
                                                    const float* __restrict__ bnw,
                                                    const float* __restrict__ bnb,
                                                    float* __restrict__ out,
                                                    float* gacc,
                                                    int* cntx,
                                                    int* cntg,
                                                    int* genx) {
    const int t = threadIdx.x;
    const int g = t & 31;    // group id (channels 4g..4g+3)
    const int sub = t >> 5;  // point slot 0..7

    // XCD batch-affinity swizzle (bijective over 1024 blocks; perf heuristic)
    const int xcd = blockIdx.x & 7;
    const int jj = blockIdx.x >> 3;                 // 0..127
    const int slot = ((xcd & 1) << 7) + jj;         // 0..255 within batch
    const int b = xcd >> 1;                         // batch 0..3
    const int pbase = (b << 13) + (slot << 5);      // batch*8192 + slot*32
    const int rowbase = b << 13;

    const float c0w = coor[g * 3 + 0];
    const float c1w = coor[g * 3 + 1];
    const float c2w = coor[g * 3 + 2];
    const float sg = scale[g];
    const float s2 = sg * sg;

    float lsum[4] = {0.f, 0.f, 0.f, 0.f};
    float lsq[4]  = {0.f, 0.f, 0.f, 0.f};
    float4 accv[4];

    // ---- phase 1: gather + encode + max over K, 8-deep explicit prefetch ----
#pragma unroll
    for (int it = 0; it < 4; ++it) {
        const int p = pbase + it * 8 + sub;
        const float* ctr = xyz + (size_t)p * 3;
        const float cx = ctr[0], cy = ctr[1], cz = ctr[2];

        const int4* kn4 = reinterpret_cast<const int4*>(knn + (size_t)p * KK);
        const int4 ka = kn4[0], kb = kn4[1], kc = kn4[2], kd = kn4[3];
        int rows[16];
        rows[0] = rowbase + ka.x;  rows[1] = rowbase + ka.y;
        rows[2] = rowbase + ka.z;  rows[3] = rowbase + ka.w;
        rows[4] = rowbase + kb.x;  rows[5] = rowbase + kb.y;
        rows[6] = rowbase + kb.z;  rows[7] = rowbase + kb.w;
        rows[8] = rowbase + kc.x;  rows[9] = rowbase + kc.y;
        rows[10] = rowbase + kc.z; rows[11] = rowbase + kc.w;
        rows[12] = rowbase + kd.x; rows[13] = rowbase + kd.y;
        rows[14] = rowbase + kd.z; rows[15] = rowbase + kd.w;

        float4 acc = make_float4(-INFINITY, -INFINITY, -INFINITY, -INFINITY);

#pragma unroll
        for (int half = 0; half < 2; ++half) {
            const int k0 = half * 8;
            float4 hv[8];
#pragma unroll
            for (int k = 0; k < 8; ++k)
                hv[k] = *reinterpret_cast<const float4*>(h + (size_t)rows[k0 + k] * 128 + g * 4);
            float ep[8];
#pragma unroll
            for (int k = 0; k < 8; ++k) {
                const float* nb = xyz + (size_t)rows[k0 + k] * 3;
                const float rx = nb[0] - cx;
                const float ry = nb[1] - cy;
                const float rz = nb[2] - cz;
                ep[k] = rx * c0w + ry * c1w + rz * c2w
                      + (rx * rx + ry * ry + rz * rz) * s2;
            }
#pragma unroll
            for (int k = 0; k < 8; ++k) {
                acc.x = fmaxf(acc.x, hv[k].x + ep[k]);
                acc.y = fmaxf(acc.y, hv[k].y + ep[k]);
                acc.z = fmaxf(acc.z, hv[k].z + ep[k]);
                acc.w = fmaxf(acc.w, hv[k].w + ep[k]);
            }
        }

        accv[it] = acc;
        lsum[0] += acc.x; lsum[1] += acc.y; lsum[2] += acc.z; lsum[3] += acc.w;
        lsq[0] += acc.x * acc.x; lsq[1] += acc.y * acc.y;
        lsq[2] += acc.z * acc.z; lsq[3] += acc.w * acc.w;
    }

    // ---- block-reduce partials in LDS, publish via RETURNING atomicAdd ----
    __shared__ float red[8][128];
    float sink = 0.f;
#pragma unroll
    for (int j = 0; j < 4; ++j) red[sub][g * 4 + j] = lsum[j];
    __syncthreads();
    if (t < 128) {
        float s = 0.f;
#pragma unroll
        for (int s8 = 0; s8 < 8; ++s8) s += red[s8][t];
        sink += __hip_atomic_fetch_add(&gacc[t * PAD], s,
                                       __ATOMIC_RELAXED, __HIP_MEMORY_SCOPE_AGENT);
    }
    __syncthreads();
#pragma unroll
    for (int j = 0; j < 4; ++j) red[sub][g * 4 + j] = lsq[j];
    __syncthreads();
    if (t < 128) {
        float q = 0.f;
#pragma unroll
        for (int s8 = 0; s8 < 8; ++s8) q += red[s8][t];
        sink += __hip_atomic_fetch_add(&gacc[(128 + t) * PAD], q,
                                       __ATOMIC_RELAXED, __HIP_MEMORY_SCOPE_AGENT);
    }
    asm volatile("" :: "v"(sink));   // keep the returns (and their waits) live
    __syncthreads();

    // ---- hierarchical grid barrier, read-based polling ----
    if (t == 0) {
        int prev = __hip_atomic_fetch_add(&cntx[xcd * PAD], 1,
                                          __ATOMIC_RELAXED, __HIP_MEMORY_SCOPE_AGENT);
        if (prev == BPX - 1) {
            int gprev = __hip_atomic_fetch_add(cntg, 1,
                                               __ATOMIC_RELAXED, __HIP_MEMORY_SCOPE_AGENT);
            if (gprev == 7) {
#pragma unroll
                for (int xx = 0; xx < 8; ++xx)
                    __hip_atomic_store(&genx[xx * PAD], 1,
                                       __ATOMIC_RELAXED, __HIP_MEMORY_SCOPE_SYSTEM);
            }
        }
        while (__hip_atomic_load(&genx[xcd * PAD],
                                 __ATOMIC_RELAXED, __HIP_MEMORY_SCOPE_SYSTEM) == 0) {
            __builtin_amdgcn_s_sleep(32);
        }
    }
    __syncthreads();

    // ---- redundant per-block stats from coherent-point loads ----
    __shared__ float sA[128], sC[128];
    if (t < 128) {
        const float stot = __hip_atomic_load(&gacc[t * PAD],
                                             __ATOMIC_RELAXED, __HIP_MEMORY_SCOPE_SYSTEM);
        const float qtot = __hip_atomic_load(&gacc[(128 + t) * PAD],
                                             __ATOMIC_RELAXED, __HIP_MEMORY_SCOPE_SYSTEM);
        const float inv_n = 1.0f / (float)NPTS;
        const float mean = stot * inv_n;
        const float var = qtot * inv_n - mean * mean;
        const float rstd = rsqrtf(var + BN_EPS);
        const float A = rstd * bnw[t];
        sA[t] = A;
        sC[t] = bnb[t] - mean * A;
    }
    __syncthreads();

    // ---- apply BN to register-resident aggregates, single write ----
    const float4 A4 = make_float4(sA[g * 4], sA[g * 4 + 1], sA[g * 4 + 2], sA[g * 4 + 3]);
    const float4 C4 = make_float4(sC[g * 4], sC[g * 4 + 1], sC[g * 4 + 2], sC[g * 4 + 3]);
#pragma unroll
    for (int it = 0; it < 4; ++it) {
        const int p = pbase + it * 8 + sub;
        float4 v = accv[it];
        v.x = fmaf(v.x, A4.x, C4.x);
        v.y = fmaf(v.y, A4.y, C4.y);
        v.z = fmaf(v.z, A4.z, C4.z);
        v.w = fmaf(v.w, A4.w, C4.w);
        *reinterpret_cast<float4*>(out + (size_t)p * 128 + g * 4) = v;
    }
}

// ---------------------------------------------------------------------------
extern "C" void kernel_launch(void* const* d_in, const int* in_sizes, int n_in,
                              void* d_out, int out_size, void* d_ws, size_t ws_size,
                              hipStream_t stream) {
    const float* x      = (const float*)d_in[0];
    const float* xyz    = (const float*)d_in[1];
    const int*   knn    = (const int*)d_in[2];
    const float* proj_w = (const float*)d_in[3];
    const float* coor   = (const float*)d_in[4];
    const float* scale  = (const float*)d_in[5];
    const float* bnw    = (const float*)d_in[6];
    const float* bnb    = (const float*)d_in[7];
    float* out = (float*)d_out;

    char* ws = (char*)d_ws;
    size_t off = 0;
    float* h    = (float*)(ws + off); off += (size_t)NPTS * DD * 4;   // 16 MB
    float* wt   = (float*)(ws + off); off += 65536;                   // 64 KB
    float* gacc = (float*)(ws + off); off += 256 * PAD * 4;           // padded sums
    int* cntx = (int*)(ws + off); off += 8 * PAD * 4;
    int* cntg = (int*)(ws + off); off += PAD * 4;
    int* genx = (int*)(ws + off); off += 8 * PAD * 4;

    transpose_w<<<64, 256, 0, stream>>>(proj_w, wt, gacc, cntx, cntg, genx);
    gemm_h<<<NPTS / 16, 256, 0, stream>>>(x, wt, h);
    fused_gbn<<<FBLOCKS, 256, 0, stream>>>(h, xyz, knn, coor, scale, bnw, bnb,
                                           out, gacc, cntx, cntg, genx);
}